// Round 7
// baseline (401.342 us; speedup 1.0000x reference)
//
#include <hip/hip_runtime.h>
#include <math.h>

// Problem constants (match reference)
#define N_NEU   8192
#define IN_SZ   512
#define OUT_SZ  512
#define N4      (N_NEU / 4)          // 2048 float4 col-quads per row
#define OUT4    (OUT_SZ / 4)         // 128 quads per W_out row
#define KPB     32                   // synapse rows per K1 block (FULL width)
#define WPB     2                    // W_in rows per K1 block
#define NBLK1   (N_NEU / KPB)        // 256 blocks = 1/CU
#define NQ      (N4 / 256)           // 8 float4 quads per thread per row
#define K2_ROWS 64                   // rows per K2 block
#define K2_BLKS (N_NEU / K2_ROWS)    // 128
constexpr float TAU_INV = 0.1f;
constexpr float G_GAIN  = 1.5f;

// ---------------------------------------------------------------------------
// K1: ROW-BLOCK split-K GEMV — the endpoint of the stream-length axis
//     (KPB 64->128->256 col-striped gave 413->392->387; this removes striding
//     entirely). Block by owns 32 complete synapse rows [by*32..) + 2 W_in
//     rows [by*2..): it streams a CONTIGUOUS 1 MB region (the fill kernels'
//     6.8 TB/s access pattern). Per thread: 8 float4 accumulators; per row,
//     8 coalesced quad-loads at col4 = j*256+tid.
//     Partials: P4[by][2048] (8 MB total, non-atomic, coalesced store).
//     Block 0 zeroes out[0:512] for K2's atomics.
// grid = 256, block = 256
// ---------------------------------------------------------------------------
__global__ __launch_bounds__(256)
void accum_kernel(const float* __restrict__ pot,
                  const float* __restrict__ inputs,
                  const float* __restrict__ synapses,
                  const float* __restrict__ W_in,
                  float4* __restrict__ P4,      // [256][2048] float4
                  float* __restrict__ out) {
    __shared__ float xs[KPB + WPB];
    const int by = blockIdx.x;
    const int tid = threadIdx.x;
    const int k0 = by * KPB;       // synapse row base
    const int w0 = by * WPB;       // W_in row base
    if (tid < KPB)                xs[tid] = G_GAIN * tanhf(pot[k0 + tid]);
    else if (tid < KPB + WPB)     xs[tid] = inputs[w0 + (tid - KPB)];
    if (by == 0 && tid < 128)
        ((float4*)out)[tid] = make_float4(0.f, 0.f, 0.f, 0.f);
    __syncthreads();

    float4 acc[NQ];
#pragma unroll
    for (int j = 0; j < NQ; ++j) acc[j] = make_float4(0.f, 0.f, 0.f, 0.f);

    const float4* Sp = (const float4*)synapses + (size_t)k0 * N4 + tid;
#pragma unroll 2
    for (int i = 0; i < KPB; ++i) {
        const float s = xs[i];
        const float4* row = Sp + (size_t)i * N4;
#pragma unroll
        for (int j = 0; j < NQ; ++j) {
            float4 m = row[j * 256];
            acc[j].x = fmaf(s, m.x, acc[j].x);
            acc[j].y = fmaf(s, m.y, acc[j].y);
            acc[j].z = fmaf(s, m.z, acc[j].z);
            acc[j].w = fmaf(s, m.w, acc[j].w);
        }
    }
    const float4* Wp = (const float4*)W_in + (size_t)w0 * N4 + tid;
#pragma unroll
    for (int i = 0; i < WPB; ++i) {
        const float s = xs[KPB + i];
        const float4* row = Wp + (size_t)i * N4;
#pragma unroll
        for (int j = 0; j < NQ; ++j) {
            float4 m = row[j * 256];
            acc[j].x = fmaf(s, m.x, acc[j].x);
            acc[j].y = fmaf(s, m.y, acc[j].y);
            acc[j].z = fmaf(s, m.z, acc[j].z);
            acc[j].w = fmaf(s, m.w, acc[j].w);
        }
    }
    float4* Pp = P4 + (size_t)by * N4 + tid;
#pragma unroll
    for (int j = 0; j < NQ; ++j) Pp[j * 256] = acc[j];   // coalesced store
}

// ---------------------------------------------------------------------------
// K2: 128 blocks x 256 thr, 64 rows each (round-4 structure, 256 tiles now).
//     Phase A: reduce 256 k-tile partials per row. Wave q (t>>6) sums 64
//       tiles with coalesced 256B reads P[(q*64+p)*8192 + k0 + r]; LDS
//       combine -> drive; pot_new -> out[512+], xs = tanh(pot_new).
//     Phase B: 64-row W_out gemv split across thread halves (h = t>>7 does
//       rows h*32..+32); LDS-combine; 128 threads atomicAdd out[0:512]
//       (65K atomics — proven-cheap level).
// grid = 128, block = 256
// ---------------------------------------------------------------------------
__global__ __launch_bounds__(256)
void finish_kernel(const float* __restrict__ pot,
                   const float* __restrict__ P,     // [256][8192] floats
                   const float* __restrict__ W_out,
                   float* __restrict__ out) {
    __shared__ float  red[256];
    __shared__ float  xs[K2_ROWS];
    __shared__ float4 hi[128];
    const int b = blockIdx.x;
    const int t = threadIdx.x;
    const int k0 = b * K2_ROWS;
    const int r = t & 63;           // row within tile (= lane)
    const int q = t >> 6;           // wave id: which 64 partial-tiles

    float s = 0.f;
#pragma unroll 8
    for (int p = 0; p < 64; ++p)
        s += P[(size_t)(q * 64 + p) * N_NEU + k0 + r];
    red[t] = s;
    __syncthreads();

    if (t < K2_ROWS) {
        float drive = red[t] + red[64 + t] + red[128 + t] + red[192 + t];
        float pv = pot[k0 + t];
        float pn = pv + (drive - pv) * TAU_INV;
        out[OUT_SZ + k0 + t] = pn;             // pot_new (exclusive rows)
        xs[t] = tanhf(pn);
    }
    __syncthreads();

    const int c4 = t & 127;         // output col4
    const int h  = t >> 7;          // row-half: 0 -> rows 0..31, 1 -> 32..63
    const float4* Wp = (const float4*)W_out + (size_t)(k0 + h * 32) * OUT4 + c4;
    float4 acc = make_float4(0.f, 0.f, 0.f, 0.f);
#pragma unroll 8
    for (int i = 0; i < 32; ++i) {
        float  sx = xs[h * 32 + i];
        float4 m  = Wp[(size_t)i * OUT4];
        acc.x = fmaf(sx, m.x, acc.x);
        acc.y = fmaf(sx, m.y, acc.y);
        acc.z = fmaf(sx, m.z, acc.z);
        acc.w = fmaf(sx, m.w, acc.w);
    }
    if (h == 1) hi[c4] = acc;
    __syncthreads();
    if (h == 0) {
        float4 o = hi[c4];
        acc.x += o.x; acc.y += o.y; acc.z += o.z; acc.w += o.w;
        float* op = out + (size_t)c4 * 4;
        atomicAdd(op + 0, acc.x);
        atomicAdd(op + 1, acc.y);
        atomicAdd(op + 2, acc.z);
        atomicAdd(op + 3, acc.w);
    }
}

// ---------------------------------------------------------------------------
extern "C" void kernel_launch(void* const* d_in, const int* in_sizes, int n_in,
                              void* d_out, int out_size, void* d_ws, size_t ws_size,
                              hipStream_t stream) {
    const float* inputs   = (const float*)d_in[0];   // [512]
    const float* pot      = (const float*)d_in[1];   // [8192]
    const float* W_in     = (const float*)d_in[2];   // [512, 8192]
    const float* synapses = (const float*)d_in[3];   // [8192, 8192]
    const float* W_out    = (const float*)d_in[4];   // [8192, 512]

    float* out = (float*)d_out;          // [0:512] output, [512:8704] pot_new
    float* P   = (float*)d_ws;           // [256][8192] partials = 8 MB

    // K1: 256 row-blocks (32 syn + 2 W_in rows each), contiguous 1 MB streams
    accum_kernel<<<dim3(NBLK1), dim3(256), 0, stream>>>(
        pot, inputs, synapses, W_in, (float4*)P, out);

    // K2: 128 tiles of 64 rows: coalesced reduce + pot_new + split-row gemv
    finish_kernel<<<dim3(K2_BLKS), dim3(256), 0, stream>>>(
        pot, P, W_out, out);
}

// Round 8
// 398.935 us; speedup vs baseline: 1.0060x; 1.0060x over previous
//
#include <hip/hip_runtime.h>
#include <math.h>

// Problem constants (match reference)
#define N_NEU   8192
#define IN_SZ   512
#define OUT_SZ  512
#define N4      (N_NEU / 4)          // 2048 float4 col-quads per row of W_in/synapses
#define OUT4    (OUT_SZ / 4)         // 128 quads per W_out row
#define KPB     256                  // synapse k-rows per K1 block
#define WPB     16                   // W_in k-rows per K1 block
#define SYN_TILES (N_NEU / KPB)      // 32 -> grid (8,32) = 256 blocks = 1/CU
#define K2_ROWS 32                   // rows per K2 block
#define K2_BLKS (N_NEU / K2_ROWS)    // 256 -> 1 block/CU (full chip)
constexpr float TAU_INV = 0.1f;
constexpr float G_GAIN  = 1.5f;

// ---------------------------------------------------------------------------
// K1: round-6 config EXACTLY (387.3 µs measured — best). Col-striped split-K,
//     KPB=256, 256 blocks = 1/CU, non-atomic partials (1 MB, L2-resident).
//     Measured axis: KPB 64/128/256 = 413/392/387; full-row blocks = 401
//     (reg pressure + 8 MB partials lose more than contiguity gains).
//     Block (0,0) zeroes out[0:512] for K2's atomics.
// grid = (8, 32), block = 256
// ---------------------------------------------------------------------------
__global__ __launch_bounds__(256)
void accum_kernel(const float* __restrict__ pot,
                  const float* __restrict__ inputs,
                  const float* __restrict__ synapses,
                  const float* __restrict__ W_in,
                  float4* __restrict__ P4,      // [32][2048] float4
                  float* __restrict__ out) {
    __shared__ float xs[KPB + WPB];
    const int bx = blockIdx.x, by = blockIdx.y;
    const int tid = threadIdx.x;
    const int k0 = by * KPB;       // synapse row base
    const int w0 = by * WPB;       // W_in row base
    xs[tid] = G_GAIN * tanhf(pot[k0 + tid]);          // all 256 threads
    if (tid < WPB) xs[KPB + tid] = inputs[w0 + tid];  // 16 W_in rows
    if (bx == 0 && by == 0 && tid < 128)
        ((float4*)out)[tid] = make_float4(0.f, 0.f, 0.f, 0.f);
    __syncthreads();

    const int col4 = bx * 256 + tid;
    const float4* Sp = (const float4*)synapses + (size_t)k0 * N4 + col4;
    const float4* Wp = (const float4*)W_in     + (size_t)w0 * N4 + col4;

    float4 acc = make_float4(0.f, 0.f, 0.f, 0.f);
#pragma unroll 8
    for (int i = 0; i < KPB; ++i) {
        float  s = xs[i];
        float4 m = Sp[(size_t)i * N4];
        acc.x = fmaf(s, m.x, acc.x);
        acc.y = fmaf(s, m.y, acc.y);
        acc.z = fmaf(s, m.z, acc.z);
        acc.w = fmaf(s, m.w, acc.w);
    }
#pragma unroll
    for (int i = 0; i < WPB; ++i) {
        float  s = xs[KPB + i];
        float4 m = Wp[(size_t)i * N4];
        acc.x = fmaf(s, m.x, acc.x);
        acc.y = fmaf(s, m.y, acc.y);
        acc.z = fmaf(s, m.z, acc.z);
        acc.w = fmaf(s, m.w, acc.w);
    }
    P4[(size_t)by * N4 + col4] = acc;          // coalesced private store
}

// ---------------------------------------------------------------------------
// K2: 256 blocks x 256 thr, 32 rows each — FULL chip (vs 128 blocks = half
//     chip in rounds 4/6). Isolated test of the K2 grid axis on the best K1
//     base (round 5 bundled this with a bad K1; never measured alone).
//     Phase A: reduce 32 k-tile partials per row. Group q = t>>5 (8 groups)
//       sums 4 tiles with 128B-coalesced reads; LDS combine -> drive;
//       pot_new -> out[512+], xs = tanh(pot_new).
//     Phase B: 32-row W_out gemv split across thread halves (h = t>>7 does
//       rows h*16..+16); LDS-combine; 128 threads atomicAdd out[0:512]
//       (131K fp32 atomics — round-2-proven harmless level).
// grid = 256, block = 256
// ---------------------------------------------------------------------------
__global__ __launch_bounds__(256)
void finish_kernel(const float* __restrict__ pot,
                   const float* __restrict__ P,     // [32][8192] floats
                   const float* __restrict__ W_out,
                   float* __restrict__ out) {
    __shared__ float  red[256];
    __shared__ float  xs[K2_ROWS];
    __shared__ float4 hi[128];
    const int b = blockIdx.x;
    const int t = threadIdx.x;
    const int k0 = b * K2_ROWS;
    const int r = t & 31;           // row within tile
    const int q = t >> 5;           // group id: which 4 partial-tiles

    float s = 0.f;
#pragma unroll
    for (int p = 0; p < 4; ++p)
        s += P[(size_t)(q * 4 + p) * N_NEU + k0 + r];
    red[t] = s;
    __syncthreads();

    if (t < K2_ROWS) {
        float drive = red[t]       + red[32 + t]  + red[64 + t]  + red[96 + t]
                    + red[128 + t] + red[160 + t] + red[192 + t] + red[224 + t];
        float pv = pot[k0 + t];
        float pn = pv + (drive - pv) * TAU_INV;
        out[OUT_SZ + k0 + t] = pn;             // pot_new (exclusive rows)
        xs[t] = tanhf(pn);
    }
    __syncthreads();

    const int c4 = t & 127;         // output col4
    const int h  = t >> 7;          // row-half: 0 -> rows 0..15, 1 -> 16..31
    const float4* Wp = (const float4*)W_out + (size_t)(k0 + h * 16) * OUT4 + c4;
    float4 acc = make_float4(0.f, 0.f, 0.f, 0.f);
#pragma unroll
    for (int i = 0; i < 16; ++i) {
        float  sx = xs[h * 16 + i];
        float4 m  = Wp[(size_t)i * OUT4];
        acc.x = fmaf(sx, m.x, acc.x);
        acc.y = fmaf(sx, m.y, acc.y);
        acc.z = fmaf(sx, m.z, acc.z);
        acc.w = fmaf(sx, m.w, acc.w);
    }
    if (h == 1) hi[c4] = acc;
    __syncthreads();
    if (h == 0) {
        float4 o = hi[c4];
        acc.x += o.x; acc.y += o.y; acc.z += o.z; acc.w += o.w;
        float* op = out + (size_t)c4 * 4;
        atomicAdd(op + 0, acc.x);
        atomicAdd(op + 1, acc.y);
        atomicAdd(op + 2, acc.z);
        atomicAdd(op + 3, acc.w);
    }
}

// ---------------------------------------------------------------------------
extern "C" void kernel_launch(void* const* d_in, const int* in_sizes, int n_in,
                              void* d_out, int out_size, void* d_ws, size_t ws_size,
                              hipStream_t stream) {
    const float* inputs   = (const float*)d_in[0];   // [512]
    const float* pot      = (const float*)d_in[1];   // [8192]
    const float* W_in     = (const float*)d_in[2];   // [512, 8192]
    const float* synapses = (const float*)d_in[3];   // [8192, 8192]
    const float* W_out    = (const float*)d_in[4];   // [8192, 512]

    float* out = (float*)d_out;          // [0:512] output, [512:8704] pot_new
    float* P   = (float*)d_ws;           // [32][8192] partials = 1 MB

    // K1: 8 col-stripes x 32 k-tiles, non-atomic partials; zeroes out[0:512]
    accum_kernel<<<dim3(8, SYN_TILES), dim3(256), 0, stream>>>(
        pot, inputs, synapses, W_in, (float4*)P, out);

    // K2: 256 tiles of 32 rows (full chip): reduce + pot_new + split-row gemv
    finish_kernel<<<dim3(K2_BLKS), dim3(256), 0, stream>>>(
        pot, P, W_out, out);
}

// Round 9
// 387.906 us; speedup vs baseline: 1.0346x; 1.0284x over previous
//
#include <hip/hip_runtime.h>
#include <math.h>

// Problem constants (match reference)
#define N_NEU   8192
#define IN_SZ   512
#define OUT_SZ  512
#define N4      (N_NEU / 4)          // 2048 float4 col-quads per row of W_in/synapses
#define OUT4    (OUT_SZ / 4)         // 128 quads per W_out row
#define KPB     256                  // synapse k-rows per K1 block
#define WPB     16                   // W_in k-rows per K1 block
#define SYN_TILES (N_NEU / KPB)      // 32 -> grid (8,32) = 256 blocks = 1/CU
#define K2_ROWS 64                   // rows per K2 block
#define K2_BLKS (N_NEU / K2_ROWS)    // 128
constexpr float TAU_INV = 0.1f;
constexpr float G_GAIN  = 1.5f;

// ---------------------------------------------------------------------------
// K1: best measured config (round 6, 387.3 µs). Col-striped split-K GEMV,
//     KPB=256, grid (8,32) = 256 blocks = 1 block/CU, non-atomic partials
//     (1 MB, L2-resident). Measured axes:
//       KPB 64/128/256 col-striped = 413/392/387; full-row blocks = 401.
//       K1 atomics instead of partials = +12 µs. 4 blocks/CU = +21..35 µs.
//     Block (0,0) zeroes out[0:512] for K2's atomics.
// grid = (8, 32), block = 256
// ---------------------------------------------------------------------------
__global__ __launch_bounds__(256)
void accum_kernel(const float* __restrict__ pot,
                  const float* __restrict__ inputs,
                  const float* __restrict__ synapses,
                  const float* __restrict__ W_in,
                  float4* __restrict__ P4,      // [32][2048] float4
                  float* __restrict__ out) {
    __shared__ float xs[KPB + WPB];
    const int bx = blockIdx.x, by = blockIdx.y;
    const int tid = threadIdx.x;
    const int k0 = by * KPB;       // synapse row base
    const int w0 = by * WPB;       // W_in row base
    xs[tid] = G_GAIN * tanhf(pot[k0 + tid]);          // all 256 threads
    if (tid < WPB) xs[KPB + tid] = inputs[w0 + tid];  // 16 W_in rows
    if (bx == 0 && by == 0 && tid < 128)
        ((float4*)out)[tid] = make_float4(0.f, 0.f, 0.f, 0.f);
    __syncthreads();

    const int col4 = bx * 256 + tid;
    const float4* Sp = (const float4*)synapses + (size_t)k0 * N4 + col4;
    const float4* Wp = (const float4*)W_in     + (size_t)w0 * N4 + col4;

    float4 acc = make_float4(0.f, 0.f, 0.f, 0.f);
#pragma unroll 8
    for (int i = 0; i < KPB; ++i) {
        float  s = xs[i];
        float4 m = Sp[(size_t)i * N4];
        acc.x = fmaf(s, m.x, acc.x);
        acc.y = fmaf(s, m.y, acc.y);
        acc.z = fmaf(s, m.z, acc.z);
        acc.w = fmaf(s, m.w, acc.w);
    }
#pragma unroll
    for (int i = 0; i < WPB; ++i) {
        float  s = xs[KPB + i];
        float4 m = Wp[(size_t)i * N4];
        acc.x = fmaf(s, m.x, acc.x);
        acc.y = fmaf(s, m.y, acc.y);
        acc.z = fmaf(s, m.z, acc.z);
        acc.w = fmaf(s, m.w, acc.w);
    }
    P4[(size_t)by * N4 + col4] = acc;          // coalesced private store
}

// ---------------------------------------------------------------------------
// K2: best measured config (round 6): 128 blocks x 256 thr, 64 rows each.
//     Measured axis: 256 blocks x 32 rows = +11.6 µs (atomic doubling +
//     shorter read runs + bigger launch tail on an 18 MB kernel).
//     Phase A: reduce the 32 k-tile partials per row. Wave q (t>>6) sums 8
//       tiles with coalesced 256B reads; LDS combine -> drive; pot_new ->
//       out[512+], xs = tanh(pot_new).
//     Phase B: 64-row W_out gemv split across thread halves (h = t>>7 does
//       rows h*32..+32); LDS-combine; 128 threads atomicAdd out[0:512]
//       (65K atomics — proven-cheap level).
// grid = 128, block = 256
// ---------------------------------------------------------------------------
__global__ __launch_bounds__(256)
void finish_kernel(const float* __restrict__ pot,
                   const float* __restrict__ P,     // [32][8192] floats
                   const float* __restrict__ W_out,
                   float* __restrict__ out) {
    __shared__ float  red[256];
    __shared__ float  xs[K2_ROWS];
    __shared__ float4 hi[128];
    const int b = blockIdx.x;
    const int t = threadIdx.x;
    const int k0 = b * K2_ROWS;
    const int r = t & 63;           // row within tile (= lane)
    const int q = t >> 6;           // wave id: which 8 partial-tiles

    float s = 0.f;
#pragma unroll
    for (int p = 0; p < 8; ++p)
        s += P[(size_t)(q * 8 + p) * N_NEU + k0 + r];
    red[t] = s;
    __syncthreads();

    if (t < K2_ROWS) {
        float drive = red[t] + red[64 + t] + red[128 + t] + red[192 + t];
        float pv = pot[k0 + t];
        float pn = pv + (drive - pv) * TAU_INV;
        out[OUT_SZ + k0 + t] = pn;             // pot_new (exclusive rows)
        xs[t] = tanhf(pn);
    }
    __syncthreads();

    const int c4 = t & 127;         // output col4
    const int h  = t >> 7;          // row-half: 0 -> rows 0..31, 1 -> 32..63
    const float4* Wp = (const float4*)W_out + (size_t)(k0 + h * 32) * OUT4 + c4;
    float4 acc = make_float4(0.f, 0.f, 0.f, 0.f);
#pragma unroll 8
    for (int i = 0; i < 32; ++i) {
        float  sx = xs[h * 32 + i];
        float4 m  = Wp[(size_t)i * OUT4];
        acc.x = fmaf(sx, m.x, acc.x);
        acc.y = fmaf(sx, m.y, acc.y);
        acc.z = fmaf(sx, m.z, acc.z);
        acc.w = fmaf(sx, m.w, acc.w);
    }
    if (h == 1) hi[c4] = acc;
    __syncthreads();
    if (h == 0) {
        float4 o = hi[c4];
        acc.x += o.x; acc.y += o.y; acc.z += o.z; acc.w += o.w;
        float* op = out + (size_t)c4 * 4;
        atomicAdd(op + 0, acc.x);
        atomicAdd(op + 1, acc.y);
        atomicAdd(op + 2, acc.z);
        atomicAdd(op + 3, acc.w);
    }
}

// ---------------------------------------------------------------------------
extern "C" void kernel_launch(void* const* d_in, const int* in_sizes, int n_in,
                              void* d_out, int out_size, void* d_ws, size_t ws_size,
                              hipStream_t stream) {
    const float* inputs   = (const float*)d_in[0];   // [512]
    const float* pot      = (const float*)d_in[1];   // [8192]
    const float* W_in     = (const float*)d_in[2];   // [512, 8192]
    const float* synapses = (const float*)d_in[3];   // [8192, 8192]
    const float* W_out    = (const float*)d_in[4];   // [8192, 512]

    float* out = (float*)d_out;          // [0:512] output, [512:8704] pot_new
    float* P   = (float*)d_ws;           // [32][8192] partials = 1 MB

    // K1: 8 col-stripes x 32 k-tiles, non-atomic partials; zeroes out[0:512]
    accum_kernel<<<dim3(8, SYN_TILES), dim3(256), 0, stream>>>(
        pot, inputs, synapses, W_in, (float4*)P, out);

    // K2: 128 tiles of 64 rows: coalesced reduce + pot_new + split-row gemv
    finish_kernel<<<dim3(K2_BLKS), dim3(256), 0, stream>>>(
        pot, P, W_out, out);
}